// Round 14
// baseline (259.118 us; speedup 1.0000x reference)
//
#include <hip/hip_runtime.h>
#include <hip/hip_bf16.h>

typedef short bf16x8 __attribute__((ext_vector_type(8)));
typedef float f32x4 __attribute__((ext_vector_type(4)));

// --- bf16 pack helpers (RNE) ----------------------------------------------
__device__ __forceinline__ unsigned pack_bf16x2(float lo, float hi) {
    unsigned a = __builtin_bit_cast(unsigned, lo);
    unsigned b = __builtin_bit_cast(unsigned, hi);
    a += 0x7fffu + ((a >> 16) & 1u);
    b += 0x7fffu + ((b >> 16) & 1u);
    return (a >> 16) | (b & 0xffff0000u);
}
__device__ __forceinline__ unsigned short bf16r(float f) {
    unsigned a = __builtin_bit_cast(unsigned, f);
    a += 0x7fffu + ((a >> 16) & 1u);
    return (unsigned short)(a >> 16);
}
__device__ __forceinline__ float bf_lo(unsigned u) {
    return __builtin_bit_cast(float, u << 16);
}
__device__ __forceinline__ float bf_hi(unsigned u) {
    return __builtin_bit_cast(float, u & 0xffff0000u);
}

// ---------------------------------------------------------------------------
// prep: pack W1/W2 into MFMA-B frag-linear bf16 layout + zero padded deg[].
// deg is PADDED: one counter per 64B line (deg_p[d*16]) — 4x fewer atomic
// RMWs per L2 line (same-line serialization was the rank_count theory).
// ---------------------------------------------------------------------------
__global__ void prep_kernel(const float* __restrict__ W1, const float* __restrict__ W2,
                            unsigned* __restrict__ Wb1, unsigned* __restrict__ Wb2,
                            int* __restrict__ deg_p, int N) {
    const int t = blockIdx.x * 256 + threadIdx.x;
    if (t < 2048) {
        const int lane = t & 63, kt = (t >> 6) & 3, ct = t >> 8;
        const int col = ct * 16 + (lane & 15);
        const int kb = 8 * (lane >> 4) + 32 * kt;
        uint4 u;
        u.x = pack_bf16x2(W1[(size_t)(kb + 0) * 128 + col], W1[(size_t)(kb + 1) * 128 + col]);
        u.y = pack_bf16x2(W1[(size_t)(kb + 2) * 128 + col], W1[(size_t)(kb + 3) * 128 + col]);
        u.z = pack_bf16x2(W1[(size_t)(kb + 4) * 128 + col], W1[(size_t)(kb + 5) * 128 + col]);
        u.w = pack_bf16x2(W1[(size_t)(kb + 6) * 128 + col], W1[(size_t)(kb + 7) * 128 + col]);
        *(uint4*)&Wb1[t * 4] = u;
    } else if (t < 3072) {
        const int s = t - 2048;
        const int lane = s & 63, kt = (s >> 6) & 3, ct = s >> 8;
        const int col = ct * 16 + (lane & 15);
        const int kb = 8 * (lane >> 4) + 32 * kt;
        uint4 u;
        u.x = pack_bf16x2(W2[(size_t)(kb + 0) * 64 + col], W2[(size_t)(kb + 1) * 64 + col]);
        u.y = pack_bf16x2(W2[(size_t)(kb + 2) * 64 + col], W2[(size_t)(kb + 3) * 64 + col]);
        u.z = pack_bf16x2(W2[(size_t)(kb + 4) * 64 + col], W2[(size_t)(kb + 5) * 64 + col]);
        u.w = pack_bf16x2(W2[(size_t)(kb + 6) * 64 + col], W2[(size_t)(kb + 7) * 64 + col]);
        *(uint4*)&Wb2[s * 4] = u;
    }
    // zero padded counters (only slot 0 of each 16-int line is used)
    for (int i = t; i < N; i += gridDim.x * 256) deg_p[(size_t)i * 16] = 0;
}

// ---------------------------------------------------------------------------
// GEMM1 + FUSED scores.  h1[N][128] bf16 = bf16(x) @ bf16(W1); es/ed[N][4]
// from fp32 accumulators (head = ct>>1 uniform per ct-tile; 16-lane reduce).
// ---------------------------------------------------------------------------
__global__ __launch_bounds__(256) void gemm1_kernel(const float* __restrict__ x,
                                                    const unsigned* __restrict__ Wb1,
                                                    const float* __restrict__ asrc,
                                                    const float* __restrict__ adst,
                                                    unsigned short* __restrict__ h1,
                                                    float* __restrict__ es,
                                                    float* __restrict__ ed,
                                                    int N) {
    const int wid = threadIdx.x >> 6, lane = threadIdx.x & 63;
    const int row0 = (blockIdx.x * 4 + wid) * 16;
    if (row0 >= N) return;
    const int g = lane >> 4, l16 = lane & 15;
    const int mrow = min(row0 + l16, N - 1);

    bf16x8 afrag[4];
#pragma unroll
    for (int kt = 0; kt < 4; ++kt) {
        const float4 v0 = *(const float4*)&x[(size_t)mrow * 128 + g * 8 + kt * 32];
        const float4 v1 = *(const float4*)&x[(size_t)mrow * 128 + g * 8 + kt * 32 + 4];
        uint4 u;
        u.x = pack_bf16x2(v0.x, v0.y);
        u.y = pack_bf16x2(v0.z, v0.w);
        u.z = pack_bf16x2(v1.x, v1.y);
        u.w = pack_bf16x2(v1.z, v1.w);
        afrag[kt] = __builtin_bit_cast(bf16x8, u);
    }
    float psh[4][4] = {};  // [head][row]
    float pdh[4][4] = {};
#pragma unroll
    for (int ct = 0; ct < 8; ++ct) {
        f32x4 acc = {0.f, 0.f, 0.f, 0.f};
#pragma unroll
        for (int kt = 0; kt < 4; ++kt) {
            const bf16x8 b = __builtin_bit_cast(bf16x8, *(const uint4*)&Wb1[((ct * 4 + kt) * 64 + lane) * 4]);
            acc = __builtin_amdgcn_mfma_f32_16x16x32_bf16(afrag[kt], b, acc, 0, 0, 0);
        }
        const int col = ct * 16 + l16;
        const float as_ = asrc[col], ad_ = adst[col];
        const int hh = ct >> 1;
#pragma unroll
        for (int r = 0; r < 4; ++r) {
            psh[hh][r] = fmaf(acc[r], as_, psh[hh][r]);
            pdh[hh][r] = fmaf(acc[r], ad_, pdh[hh][r]);
        }
#pragma unroll
        for (int r = 0; r < 4; ++r) {
            const int row = row0 + g * 4 + r;
            if (row < N) h1[(size_t)row * 128 + col] = bf16r(acc[r]);
        }
    }
#pragma unroll
    for (int hh = 0; hh < 4; ++hh)
#pragma unroll
        for (int r = 0; r < 4; ++r) {
#pragma unroll
            for (int off = 1; off <= 8; off <<= 1) {
                psh[hh][r] += __shfl_xor(psh[hh][r], off);
                pdh[hh][r] += __shfl_xor(pdh[hh][r], off);
            }
        }
    if (l16 == 0) {
#pragma unroll
        for (int r = 0; r < 4; ++r) {
            const int row = row0 + g * 4 + r;
            if (row < N) {
#pragma unroll
                for (int hh = 0; hh < 4; ++hh) {
                    es[row * 4 + hh] = psh[hh][r];
                    ed[row * 4 + hh] = pdh[hh][r];
                }
            }
        }
    }
}

// ---------------------------------------------------------------------------
// GEMM2 + FUSED scores (single head): h2[N][64] bf16 = x2(bf16) @ bf16(W2).
// ---------------------------------------------------------------------------
__global__ __launch_bounds__(256) void gemm2_kernel(const unsigned* __restrict__ x2p,
                                                    const unsigned* __restrict__ Wb2,
                                                    const float* __restrict__ asrc,
                                                    const float* __restrict__ adst,
                                                    unsigned short* __restrict__ h2,
                                                    float* __restrict__ es,
                                                    float* __restrict__ ed,
                                                    int N) {
    const int wid = threadIdx.x >> 6, lane = threadIdx.x & 63;
    const int row0 = (blockIdx.x * 4 + wid) * 16;
    if (row0 >= N) return;
    const int g = lane >> 4, l16 = lane & 15;
    const int mrow = min(row0 + l16, N - 1);

    bf16x8 afrag[4];
#pragma unroll
    for (int kt = 0; kt < 4; ++kt)
        afrag[kt] = __builtin_bit_cast(bf16x8, *(const uint4*)&x2p[(size_t)mrow * 64 + g * 4 + kt * 16]);
    float ps[4] = {}, pd[4] = {};
#pragma unroll
    for (int ct = 0; ct < 4; ++ct) {
        f32x4 acc = {0.f, 0.f, 0.f, 0.f};
#pragma unroll
        for (int kt = 0; kt < 4; ++kt) {
            const bf16x8 b = __builtin_bit_cast(bf16x8, *(const uint4*)&Wb2[((ct * 4 + kt) * 64 + lane) * 4]);
            acc = __builtin_amdgcn_mfma_f32_16x16x32_bf16(afrag[kt], b, acc, 0, 0, 0);
        }
        const int col = ct * 16 + l16;
        const float as_ = asrc[col], ad_ = adst[col];
#pragma unroll
        for (int r = 0; r < 4; ++r) {
            ps[r] = fmaf(acc[r], as_, ps[r]);
            pd[r] = fmaf(acc[r], ad_, pd[r]);
        }
#pragma unroll
        for (int r = 0; r < 4; ++r) {
            const int row = row0 + g * 4 + r;
            if (row < N) h2[(size_t)row * 64 + col] = bf16r(acc[r]);
        }
    }
#pragma unroll
    for (int r = 0; r < 4; ++r) {
#pragma unroll
        for (int off = 1; off <= 8; off <<= 1) {
            ps[r] += __shfl_xor(ps[r], off);
            pd[r] += __shfl_xor(pd[r], off);
        }
    }
    if (l16 == 0) {
#pragma unroll
        for (int r = 0; r < 4; ++r) {
            const int row = row0 + g * 4 + r;
            if (row < N) { es[row] = ps[r]; ed[row] = pd[r]; }
        }
    }
}

// ---------------------------------------------------------------------------
// rank_count, padded counters + contiguous chunks: thread t owns edges
// [8t, 8t+8) -> coalesced ei reads & rank writes, 8 returning atomics in
// flight, counters on distinct 64B lines (deg_p[d*16]).
// ---------------------------------------------------------------------------
__global__ __launch_bounds__(256) void rank_count_kernel(const int* __restrict__ ei, int E,
                                                         int* __restrict__ deg_p,
                                                         int* __restrict__ rank) {
    const int base = (blockIdx.x * 256 + threadIdx.x) * 8;
    if (base >= E) return;
    if (base + 8 <= E) {
        int d[8], r[8];
#pragma unroll
        for (int i = 0; i < 8; ++i) d[i] = ei[E + base + i];
#pragma unroll
        for (int i = 0; i < 8; ++i) r[i] = atomicAdd(&deg_p[(size_t)d[i] * 16], 1);
#pragma unroll
        for (int i = 0; i < 8; ++i) rank[base + i] = r[i];
    } else {
        for (int e = base; e < E; ++e)
            rank[e] = atomicAdd(&deg_p[(size_t)ei[E + e] * 16], 1);
    }
}

// ---------------------------------------------------------------------------
// CSR scan: exclusive scan of (deg_p[i*16]+1); self-loop takes LAST slot.
// ---------------------------------------------------------------------------
__global__ __launch_bounds__(256) void scan_p1_kernel(const int* __restrict__ deg_p,
                                                      int* __restrict__ excl,
                                                      int* __restrict__ bsum, int N) {
    __shared__ int lds[256];
    const int tid = threadIdx.x;
    const int base = blockIdx.x * 2048;
    const int idx0 = base + tid * 8;
    int v[8];
    int s = 0;
#pragma unroll
    for (int i = 0; i < 8; ++i) {
        v[i] = (idx0 + i < N) ? deg_p[(size_t)(idx0 + i) * 16] + 1 : 0;  // +1 = self-loop
        s += v[i];
    }
    lds[tid] = s;
    __syncthreads();
    for (int off = 1; off < 256; off <<= 1) {
        int t = (tid >= off) ? lds[tid - off] : 0;
        __syncthreads();
        lds[tid] += t;
        __syncthreads();
    }
    const int texcl = lds[tid] - s;
    if (tid == 255) bsum[blockIdx.x] = lds[255];
    int run = texcl;
#pragma unroll
    for (int i = 0; i < 8; ++i) {
        if (idx0 + i < N) excl[idx0 + i] = run;
        run += v[i];
    }
}

__global__ void scan_p2_kernel(int* __restrict__ bsum, int nchunks) {
    const int lane = threadIdx.x;
    int v = (lane < nchunks) ? bsum[lane] : 0;
    const int orig = v;
#pragma unroll
    for (int off = 1; off < 64; off <<= 1) {
        int t = __shfl_up(v, off);
        if (lane >= off) v += t;
    }
    if (lane < nchunks) bsum[lane] = v - orig;
}

__global__ void scan_p3_kernel(const int* __restrict__ excl, const int* __restrict__ bsum,
                               int* __restrict__ rowstart, int N, int Etot) {
    const int i = blockIdx.x * 256 + threadIdx.x;
    if (i < N) rowstart[i] = excl[i] + bsum[i >> 11];
    if (i == 0) rowstart[N] = Etot;
}

__global__ void csr_fill_kernel(const int* __restrict__ ei, int E, int N,
                                const int* __restrict__ rowstart,
                                const int* __restrict__ rank,
                                int* __restrict__ csr_src) {
    const int e = blockIdx.x * 256 + threadIdx.x;
    if (e < E) {
        const int d = ei[E + e];
        csr_src[rowstart[d] + rank[e]] = ei[e];
    } else if (e < E + N) {
        const int d = e - E;
        csr_src[rowstart[d + 1] - 1] = d;
    }
}

// ---------------------------------------------------------------------------
// Aggregation layer 1, GROUPED: 4 nodes/wave, 16 lanes/node, lane = 8 ch
// (uint4 gather).  4-edge unroll; invalid slots get p=0 (branch-free).
// ~5.9 TB/s effective gather — near the random-gather floor for bf16 rows.
// ---------------------------------------------------------------------------
__global__ __launch_bounds__(256) void aggregate1_kernel(const unsigned* __restrict__ h1p,
                                                         const float* __restrict__ es,
                                                         const float* __restrict__ ed,
                                                         const int* __restrict__ rowstart,
                                                         const int* __restrict__ csr_src,
                                                         const float* __restrict__ b,
                                                         unsigned* __restrict__ x2p, int N) {
    const int lane = threadIdx.x & 63;
    const int w = (blockIdx.x * 256 + threadIdx.x) >> 6;
    const int l16 = lane & 15;
    const int n = w * 4 + (lane >> 4);
    const int hh = l16 >> 2;  // head 0..3
    const bool valid = n < N;
    const int nc = valid ? n : N - 1;
    const int beg = rowstart[nc];
    const int deg = valid ? rowstart[nc + 1] - beg : 0;
    const float edv = ed[nc * 4 + hh];

    int dmax = deg;
    dmax = max(dmax, __shfl_xor(dmax, 16));
    dmax = max(dmax, __shfl_xor(dmax, 32));

    float acc0 = 0.f, acc1 = 0.f, acc2 = 0.f, acc3 = 0.f;
    float acc4 = 0.f, acc5 = 0.f, acc6 = 0.f, acc7 = 0.f;
    float den = 0.f;
    for (int j = 0; j < dmax; j += 4) {
        const bool va = j < deg, vb = j + 1 < deg, vc = j + 2 < deg, vd = j + 3 < deg;
        const int pa_ = va ? beg + j : 0;
        const int pb_ = vb ? beg + j + 1 : 0;
        const int pc_ = vc ? beg + j + 2 : 0;
        const int pd_ = vd ? beg + j + 3 : 0;
        const int sa = csr_src[pa_];
        const int sb = csr_src[pb_];
        const int sc = csr_src[pc_];
        const int sd = csr_src[pd_];
        const uint4 ua = *(const uint4*)&h1p[(size_t)sa * 64 + l16 * 4];
        const uint4 ub = *(const uint4*)&h1p[(size_t)sb * 64 + l16 * 4];
        const uint4 uc = *(const uint4*)&h1p[(size_t)sc * 64 + l16 * 4];
        const uint4 ud = *(const uint4*)&h1p[(size_t)sd * 64 + l16 * 4];
        const float xa = es[sa * 4 + hh] + edv;
        const float xb = es[sb * 4 + hh] + edv;
        const float xc = es[sc * 4 + hh] + edv;
        const float xd = es[sd * 4 + hh] + edv;
        float qa = __expf(fmaxf(xa, 0.2f * xa));
        float qb = __expf(fmaxf(xb, 0.2f * xb));
        float qc = __expf(fmaxf(xc, 0.2f * xc));
        float qd = __expf(fmaxf(xd, 0.2f * xd));
        qa = va ? qa : 0.f;
        qb = vb ? qb : 0.f;
        qc = vc ? qc : 0.f;
        qd = vd ? qd : 0.f;
        den += (qa + qb) + (qc + qd);
        acc0 = fmaf(qa, bf_lo(ua.x), fmaf(qb, bf_lo(ub.x), fmaf(qc, bf_lo(uc.x), fmaf(qd, bf_lo(ud.x), acc0))));
        acc1 = fmaf(qa, bf_hi(ua.x), fmaf(qb, bf_hi(ub.x), fmaf(qc, bf_hi(uc.x), fmaf(qd, bf_hi(ud.x), acc1))));
        acc2 = fmaf(qa, bf_lo(ua.y), fmaf(qb, bf_lo(ub.y), fmaf(qc, bf_lo(uc.y), fmaf(qd, bf_lo(ud.y), acc2))));
        acc3 = fmaf(qa, bf_hi(ua.y), fmaf(qb, bf_hi(ub.y), fmaf(qc, bf_hi(uc.y), fmaf(qd, bf_hi(ud.y), acc3))));
        acc4 = fmaf(qa, bf_lo(ua.z), fmaf(qb, bf_lo(ub.z), fmaf(qc, bf_lo(uc.z), fmaf(qd, bf_lo(ud.z), acc4))));
        acc5 = fmaf(qa, bf_hi(ua.z), fmaf(qb, bf_hi(ub.z), fmaf(qc, bf_hi(uc.z), fmaf(qd, bf_hi(ud.z), acc5))));
        acc6 = fmaf(qa, bf_lo(ua.w), fmaf(qb, bf_lo(ub.w), fmaf(qc, bf_lo(uc.w), fmaf(qd, bf_lo(ud.w), acc6))));
        acc7 = fmaf(qa, bf_hi(ua.w), fmaf(qb, bf_hi(ub.w), fmaf(qc, bf_hi(uc.w), fmaf(qd, bf_hi(ud.w), acc7))));
    }
    if (valid) {
        const float inv = __builtin_amdgcn_rcpf(den);
        const float4 ba = *(const float4*)&b[l16 * 8];
        const float4 bb = *(const float4*)&b[l16 * 8 + 4];
        float o0 = fmaf(acc0, inv, ba.x); o0 = fmaxf(o0, 0.01f * o0);
        float o1 = fmaf(acc1, inv, ba.y); o1 = fmaxf(o1, 0.01f * o1);
        float o2 = fmaf(acc2, inv, ba.z); o2 = fmaxf(o2, 0.01f * o2);
        float o3 = fmaf(acc3, inv, ba.w); o3 = fmaxf(o3, 0.01f * o3);
        float o4 = fmaf(acc4, inv, bb.x); o4 = fmaxf(o4, 0.01f * o4);
        float o5 = fmaf(acc5, inv, bb.y); o5 = fmaxf(o5, 0.01f * o5);
        float o6 = fmaf(acc6, inv, bb.z); o6 = fmaxf(o6, 0.01f * o6);
        float o7 = fmaf(acc7, inv, bb.w); o7 = fmaxf(o7, 0.01f * o7);
        uint4 o;
        o.x = pack_bf16x2(o0, o1);
        o.y = pack_bf16x2(o2, o3);
        o.z = pack_bf16x2(o4, o5);
        o.w = pack_bf16x2(o6, o7);
        *(uint4*)&x2p[(size_t)n * 64 + l16 * 4] = o;
    }
}

// ---------------------------------------------------------------------------
// Aggregation layer 2, GROUPED: 4 nodes/wave, 16 lanes/node, lane = 4 ch
// (uint2 gather).  Single head.  4-edge unroll.
// ---------------------------------------------------------------------------
__global__ __launch_bounds__(256) void aggregate2_kernel(const unsigned* __restrict__ h2p,
                                                         const float* __restrict__ es,
                                                         const float* __restrict__ ed,
                                                         const int* __restrict__ rowstart,
                                                         const int* __restrict__ csr_src,
                                                         const float* __restrict__ b,
                                                         float* __restrict__ out, int N) {
    const int lane = threadIdx.x & 63;
    const int w = (blockIdx.x * 256 + threadIdx.x) >> 6;
    const int l16 = lane & 15;
    const int n = w * 4 + (lane >> 4);
    const bool valid = n < N;
    const int nc = valid ? n : N - 1;
    const int beg = rowstart[nc];
    const int deg = valid ? rowstart[nc + 1] - beg : 0;
    const float edv = ed[nc];

    int dmax = deg;
    dmax = max(dmax, __shfl_xor(dmax, 16));
    dmax = max(dmax, __shfl_xor(dmax, 32));

    float acc0 = 0.f, acc1 = 0.f, acc2 = 0.f, acc3 = 0.f;
    float den = 0.f;
    for (int j = 0; j < dmax; j += 4) {
        const bool va = j < deg, vb = j + 1 < deg, vc = j + 2 < deg, vd = j + 3 < deg;
        const int pa_ = va ? beg + j : 0;
        const int pb_ = vb ? beg + j + 1 : 0;
        const int pc_ = vc ? beg + j + 2 : 0;
        const int pd_ = vd ? beg + j + 3 : 0;
        const int sa = csr_src[pa_];
        const int sb = csr_src[pb_];
        const int sc = csr_src[pc_];
        const int sd = csr_src[pd_];
        const uint2 ua = *(const uint2*)&h2p[(size_t)sa * 32 + l16 * 2];
        const uint2 ub = *(const uint2*)&h2p[(size_t)sb * 32 + l16 * 2];
        const uint2 uc = *(const uint2*)&h2p[(size_t)sc * 32 + l16 * 2];
        const uint2 ud = *(const uint2*)&h2p[(size_t)sd * 32 + l16 * 2];
        const float xa = es[sa] + edv;
        const float xb = es[sb] + edv;
        const float xc = es[sc] + edv;
        const float xd = es[sd] + edv;
        float qa = __expf(fmaxf(xa, 0.2f * xa));
        float qb = __expf(fmaxf(xb, 0.2f * xb));
        float qc = __expf(fmaxf(xc, 0.2f * xc));
        float qd = __expf(fmaxf(xd, 0.2f * xd));
        qa = va ? qa : 0.f;
        qb = vb ? qb : 0.f;
        qc = vc ? qc : 0.f;
        qd = vd ? qd : 0.f;
        den += (qa + qb) + (qc + qd);
        acc0 = fmaf(qa, bf_lo(ua.x), fmaf(qb, bf_lo(ub.x), fmaf(qc, bf_lo(uc.x), fmaf(qd, bf_lo(ud.x), acc0))));
        acc1 = fmaf(qa, bf_hi(ua.x), fmaf(qb, bf_hi(ub.x), fmaf(qc, bf_hi(uc.x), fmaf(qd, bf_hi(ud.x), acc1))));
        acc2 = fmaf(qa, bf_lo(ua.y), fmaf(qb, bf_lo(ub.y), fmaf(qc, bf_lo(uc.y), fmaf(qd, bf_lo(ud.y), acc2))));
        acc3 = fmaf(qa, bf_hi(ua.y), fmaf(qb, bf_hi(ub.y), fmaf(qc, bf_hi(uc.y), fmaf(qd, bf_hi(ud.y), acc3))));
    }
    if (valid) {
        const float inv = __builtin_amdgcn_rcpf(den);
        const float4 bv = *(const float4*)&b[l16 * 4];
        float4 o;
        o.x = fmaf(acc0, inv, bv.x);
        o.y = fmaf(acc1, inv, bv.y);
        o.z = fmaf(acc2, inv, bv.z);
        o.w = fmaf(acc3, inv, bv.w);
        *(float4*)&out[(size_t)n * 64 + l16 * 4] = o;
    }
}

// ---------------------------------------------------------------------------
extern "C" void kernel_launch(void* const* d_in, const int* in_sizes, int n_in,
                              void* d_out, int out_size, void* d_ws, size_t ws_size,
                              hipStream_t stream) {
    const float* x     = (const float*)d_in[0];
    const int*   ei    = (const int*)d_in[1];
    const float* W1    = (const float*)d_in[2];
    const float* asrc1 = (const float*)d_in[3];
    const float* adst1 = (const float*)d_in[4];
    const float* b1    = (const float*)d_in[5];
    const float* W2    = (const float*)d_in[6];
    const float* asrc2 = (const float*)d_in[7];
    const float* adst2 = (const float*)d_in[8];
    const float* b2    = (const float*)d_in[9];
    float* out = (float*)d_out;

    const int N = in_sizes[0] / 128;
    const int E = in_sizes[1] / 2;
    const int Etot = E + N;

    // workspace layout (~90 MB)
    char* p = (char*)d_ws;
    auto alloc = [&](size_t bytes) {
        char* q = p;
        p += (bytes + 255) & ~size_t(255);
        return q;
    };
    unsigned short* h1 = (unsigned short*)alloc((size_t)N * 128 * 2);  // bf16 h1
    unsigned* x2p      = (unsigned*)alloc((size_t)N * 64 * 4);         // bf16x2 x2
    unsigned short* h2 = (unsigned short*)alloc((size_t)N * 64 * 2);   // bf16 h2
    float* es1      = (float*)alloc((size_t)N * 4 * 4);
    float* ed1      = (float*)alloc((size_t)N * 4 * 4);
    float* es2      = (float*)alloc((size_t)N * 4);
    float* ed2      = (float*)alloc((size_t)N * 4);
    int*   deg_p    = (int*)alloc((size_t)N * 64);   // PADDED: 1 counter / 64B line
    int*   excl     = (int*)alloc((size_t)N * 4);
    int*   bsum     = (int*)alloc(1024);
    int*   rowstart = (int*)alloc((size_t)(N + 1) * 4);
    int*   rank     = (int*)alloc((size_t)E * 4);
    int*   csr_src  = (int*)alloc((size_t)Etot * 4);
    unsigned* Wb1   = (unsigned*)alloc(2048 * 16);
    unsigned* Wb2   = (unsigned*)alloc(1024 * 16);

    const int nblk16 = (N + 63) / 64;       // MFMA gemms: 4 waves x 16 rows
    const int nwb4 = (N + 15) / 16;         // 4-nodes-per-wave agg kernels
    const int nrank = (E + 2047) / 2048;    // 8 contiguous edges per thread
    const int nchunks = (N + 2047) / 2048;  // <= 64 required (N <= 131072)

    // weight prep + padded-deg zero-init (fused)
    prep_kernel<<<64, 256, 0, stream>>>(W1, W2, Wb1, Wb2, deg_p, N);

    // layer 1 projection (MFMA) + fused scores
    gemm1_kernel<<<nblk16, 256, 0, stream>>>(x, Wb1, asrc1, adst1, h1, es1, ed1, N);

    // CSR by destination (shared by both layers)
    rank_count_kernel<<<nrank, 256, 0, stream>>>(ei, E, deg_p, rank);
    scan_p1_kernel<<<nchunks, 256, 0, stream>>>(deg_p, excl, bsum, N);
    scan_p2_kernel<<<1, 64, 0, stream>>>(bsum, nchunks);
    scan_p3_kernel<<<(N + 255) / 256, 256, 0, stream>>>(excl, bsum, rowstart, N, Etot);
    csr_fill_kernel<<<(Etot + 255) / 256, 256, 0, stream>>>(ei, E, N, rowstart, rank, csr_src);

    // layer 1 aggregation (grouped, 4-edge ILP)
    aggregate1_kernel<<<nwb4, 256, 0, stream>>>((const unsigned*)h1, es1, ed1,
                                                rowstart, csr_src, b1, x2p, N);

    // layer 2
    gemm2_kernel<<<nblk16, 256, 0, stream>>>(x2p, Wb2, asrc2, adst2, h2, es2, ed2, N);
    aggregate2_kernel<<<nwb4, 256, 0, stream>>>((const unsigned*)h2, es2, ed2,
                                                rowstart, csr_src, b2, out, N);
}

// Round 15
// 228.035 us; speedup vs baseline: 1.1363x; 1.1363x over previous
//
#include <hip/hip_runtime.h>
#include <hip/hip_bf16.h>

typedef short bf16x8 __attribute__((ext_vector_type(8)));
typedef float f32x4 __attribute__((ext_vector_type(4)));

// --- bf16 pack helpers (RNE) ----------------------------------------------
__device__ __forceinline__ unsigned pack_bf16x2(float lo, float hi) {
    unsigned a = __builtin_bit_cast(unsigned, lo);
    unsigned b = __builtin_bit_cast(unsigned, hi);
    a += 0x7fffu + ((a >> 16) & 1u);
    b += 0x7fffu + ((b >> 16) & 1u);
    return (a >> 16) | (b & 0xffff0000u);
}
__device__ __forceinline__ unsigned short bf16r(float f) {
    unsigned a = __builtin_bit_cast(unsigned, f);
    a += 0x7fffu + ((a >> 16) & 1u);
    return (unsigned short)(a >> 16);
}
__device__ __forceinline__ float bf_lo(unsigned u) {
    return __builtin_bit_cast(float, u << 16);
}
__device__ __forceinline__ float bf_hi(unsigned u) {
    return __builtin_bit_cast(float, u & 0xffff0000u);
}

// ---------------------------------------------------------------------------
// prep: pack W1/W2 into MFMA-B frag-linear bf16 layout + zero the 512 bucket
// counters (the CSR build is now a two-level bucket sort, no per-edge fabric
// atomics).
// ---------------------------------------------------------------------------
__global__ void prep_kernel(const float* __restrict__ W1, const float* __restrict__ W2,
                            unsigned* __restrict__ Wb1, unsigned* __restrict__ Wb2,
                            int* __restrict__ gcount) {
    const int t = blockIdx.x * 256 + threadIdx.x;
    if (t < 2048) {
        const int lane = t & 63, kt = (t >> 6) & 3, ct = t >> 8;
        const int col = ct * 16 + (lane & 15);
        const int kb = 8 * (lane >> 4) + 32 * kt;
        uint4 u;
        u.x = pack_bf16x2(W1[(size_t)(kb + 0) * 128 + col], W1[(size_t)(kb + 1) * 128 + col]);
        u.y = pack_bf16x2(W1[(size_t)(kb + 2) * 128 + col], W1[(size_t)(kb + 3) * 128 + col]);
        u.z = pack_bf16x2(W1[(size_t)(kb + 4) * 128 + col], W1[(size_t)(kb + 5) * 128 + col]);
        u.w = pack_bf16x2(W1[(size_t)(kb + 6) * 128 + col], W1[(size_t)(kb + 7) * 128 + col]);
        *(uint4*)&Wb1[t * 4] = u;
    } else if (t < 3072) {
        const int s = t - 2048;
        const int lane = s & 63, kt = (s >> 6) & 3, ct = s >> 8;
        const int col = ct * 16 + (lane & 15);
        const int kb = 8 * (lane >> 4) + 32 * kt;
        uint4 u;
        u.x = pack_bf16x2(W2[(size_t)(kb + 0) * 64 + col], W2[(size_t)(kb + 1) * 64 + col]);
        u.y = pack_bf16x2(W2[(size_t)(kb + 2) * 64 + col], W2[(size_t)(kb + 3) * 64 + col]);
        u.z = pack_bf16x2(W2[(size_t)(kb + 4) * 64 + col], W2[(size_t)(kb + 5) * 64 + col]);
        u.w = pack_bf16x2(W2[(size_t)(kb + 6) * 64 + col], W2[(size_t)(kb + 7) * 64 + col]);
        *(uint4*)&Wb2[s * 4] = u;
    }
    if (t < 512) gcount[t] = 0;
}

// ---------------------------------------------------------------------------
// GEMM1 + FUSED scores.  h1[N][128] bf16 = bf16(x) @ bf16(W1); es/ed[N][4]
// from fp32 accumulators (head = ct>>1 uniform per ct-tile; 16-lane reduce).
// ---------------------------------------------------------------------------
__global__ __launch_bounds__(256) void gemm1_kernel(const float* __restrict__ x,
                                                    const unsigned* __restrict__ Wb1,
                                                    const float* __restrict__ asrc,
                                                    const float* __restrict__ adst,
                                                    unsigned short* __restrict__ h1,
                                                    float* __restrict__ es,
                                                    float* __restrict__ ed,
                                                    int N) {
    const int wid = threadIdx.x >> 6, lane = threadIdx.x & 63;
    const int row0 = (blockIdx.x * 4 + wid) * 16;
    if (row0 >= N) return;
    const int g = lane >> 4, l16 = lane & 15;
    const int mrow = min(row0 + l16, N - 1);

    bf16x8 afrag[4];
#pragma unroll
    for (int kt = 0; kt < 4; ++kt) {
        const float4 v0 = *(const float4*)&x[(size_t)mrow * 128 + g * 8 + kt * 32];
        const float4 v1 = *(const float4*)&x[(size_t)mrow * 128 + g * 8 + kt * 32 + 4];
        uint4 u;
        u.x = pack_bf16x2(v0.x, v0.y);
        u.y = pack_bf16x2(v0.z, v0.w);
        u.z = pack_bf16x2(v1.x, v1.y);
        u.w = pack_bf16x2(v1.z, v1.w);
        afrag[kt] = __builtin_bit_cast(bf16x8, u);
    }
    float psh[4][4] = {};  // [head][row]
    float pdh[4][4] = {};
#pragma unroll
    for (int ct = 0; ct < 8; ++ct) {
        f32x4 acc = {0.f, 0.f, 0.f, 0.f};
#pragma unroll
        for (int kt = 0; kt < 4; ++kt) {
            const bf16x8 b = __builtin_bit_cast(bf16x8, *(const uint4*)&Wb1[((ct * 4 + kt) * 64 + lane) * 4]);
            acc = __builtin_amdgcn_mfma_f32_16x16x32_bf16(afrag[kt], b, acc, 0, 0, 0);
        }
        const int col = ct * 16 + l16;
        const float as_ = asrc[col], ad_ = adst[col];
        const int hh = ct >> 1;
#pragma unroll
        for (int r = 0; r < 4; ++r) {
            psh[hh][r] = fmaf(acc[r], as_, psh[hh][r]);
            pdh[hh][r] = fmaf(acc[r], ad_, pdh[hh][r]);
        }
#pragma unroll
        for (int r = 0; r < 4; ++r) {
            const int row = row0 + g * 4 + r;
            if (row < N) h1[(size_t)row * 128 + col] = bf16r(acc[r]);
        }
    }
#pragma unroll
    for (int hh = 0; hh < 4; ++hh)
#pragma unroll
        for (int r = 0; r < 4; ++r) {
#pragma unroll
            for (int off = 1; off <= 8; off <<= 1) {
                psh[hh][r] += __shfl_xor(psh[hh][r], off);
                pdh[hh][r] += __shfl_xor(pdh[hh][r], off);
            }
        }
    if (l16 == 0) {
#pragma unroll
        for (int r = 0; r < 4; ++r) {
            const int row = row0 + g * 4 + r;
            if (row < N) {
#pragma unroll
                for (int hh = 0; hh < 4; ++hh) {
                    es[row * 4 + hh] = psh[hh][r];
                    ed[row * 4 + hh] = pdh[hh][r];
                }
            }
        }
    }
}

// ---------------------------------------------------------------------------
// GEMM2 + FUSED scores (single head): h2[N][64] bf16 = x2(bf16) @ bf16(W2).
// ---------------------------------------------------------------------------
__global__ __launch_bounds__(256) void gemm2_kernel(const unsigned* __restrict__ x2p,
                                                    const unsigned* __restrict__ Wb2,
                                                    const float* __restrict__ asrc,
                                                    const float* __restrict__ adst,
                                                    unsigned short* __restrict__ h2,
                                                    float* __restrict__ es,
                                                    float* __restrict__ ed,
                                                    int N) {
    const int wid = threadIdx.x >> 6, lane = threadIdx.x & 63;
    const int row0 = (blockIdx.x * 4 + wid) * 16;
    if (row0 >= N) return;
    const int g = lane >> 4, l16 = lane & 15;
    const int mrow = min(row0 + l16, N - 1);

    bf16x8 afrag[4];
#pragma unroll
    for (int kt = 0; kt < 4; ++kt)
        afrag[kt] = __builtin_bit_cast(bf16x8, *(const uint4*)&x2p[(size_t)mrow * 64 + g * 4 + kt * 16]);
    float ps[4] = {}, pd[4] = {};
#pragma unroll
    for (int ct = 0; ct < 4; ++ct) {
        f32x4 acc = {0.f, 0.f, 0.f, 0.f};
#pragma unroll
        for (int kt = 0; kt < 4; ++kt) {
            const bf16x8 b = __builtin_bit_cast(bf16x8, *(const uint4*)&Wb2[((ct * 4 + kt) * 64 + lane) * 4]);
            acc = __builtin_amdgcn_mfma_f32_16x16x32_bf16(afrag[kt], b, acc, 0, 0, 0);
        }
        const int col = ct * 16 + l16;
        const float as_ = asrc[col], ad_ = adst[col];
#pragma unroll
        for (int r = 0; r < 4; ++r) {
            ps[r] = fmaf(acc[r], as_, ps[r]);
            pd[r] = fmaf(acc[r], ad_, pd[r]);
        }
#pragma unroll
        for (int r = 0; r < 4; ++r) {
            const int row = row0 + g * 4 + r;
            if (row < N) h2[(size_t)row * 64 + col] = bf16r(acc[r]);
        }
    }
#pragma unroll
    for (int r = 0; r < 4; ++r) {
#pragma unroll
        for (int off = 1; off <= 8; off <<= 1) {
            ps[r] += __shfl_xor(ps[r], off);
            pd[r] += __shfl_xor(pd[r], off);
        }
    }
    if (l16 == 0) {
#pragma unroll
        for (int r = 0; r < 4; ++r) {
            const int row = row0 + g * 4 + r;
            if (row < N) { es[row] = ps[r]; ed[row] = pd[r]; }
        }
    }
}

// ---------------------------------------------------------------------------
// CSR build, two-level bucket sort (hi = dst>>8, NB = ceil(N/256) <= 512).
// Replaces the per-edge returning-atomic pipeline: local ranks live in LDS;
// only ~NB global returning atomics per scatter block.
// ---------------------------------------------------------------------------

// Stage 1: histogram of REAL edges per hi-bucket (LDS-aggregated).
__global__ __launch_bounds__(256) void bucket_hist_kernel(const int* __restrict__ ei, int E,
                                                          int* __restrict__ gcount) {
    __shared__ int h[512];
    for (int i = threadIdx.x; i < 512; i += 256) h[i] = 0;
    __syncthreads();
    for (int e = blockIdx.x * 256 + threadIdx.x; e < E; e += gridDim.x * 256)
        atomicAdd(&h[ei[E + e] >> 8], 1);
    __syncthreads();
    for (int i = threadIdx.x; i < 512; i += 256)
        if (h[i]) atomicAdd(&gcount[i], h[i]);
}

// Stage 2 (1 block): counts += per-bucket self-loop count, exclusive scan ->
// bucket_base[0..NB] (slot space), zero cursors, rowstart[N] = Etot.
__global__ __launch_bounds__(256) void bucket_scan_kernel(const int* __restrict__ gcount,
                                                          int* __restrict__ bucket_base,
                                                          int* __restrict__ cursor,
                                                          int* __restrict__ rowstart,
                                                          int N, int NB, int Etot) {
    __shared__ int pairs[256];
    const int t = threadIdx.x;
    const int b0 = 2 * t, b1 = 2 * t + 1;
    int v0 = 0, v1 = 0;
    if (b0 < NB) v0 = gcount[b0] + min(256, N - b0 * 256);  // + self-loops
    if (b1 < NB) v1 = gcount[b1] + min(256, N - b1 * 256);
    const int s = v0 + v1;
    pairs[t] = s;
    __syncthreads();
    for (int off = 1; off < 256; off <<= 1) {
        int tv = (t >= off) ? pairs[t - off] : 0;
        __syncthreads();
        pairs[t] += tv;
        __syncthreads();
    }
    const int base = pairs[t] - s;  // exclusive over pairs
    if (b0 < NB) bucket_base[b0] = base;
    if (b1 < NB) bucket_base[b1] = base + v0;
    if (t == 255) {
        bucket_base[NB] = pairs[255];  // == Etot
        rowstart[N] = Etot;
    }
    cursor[b0] = 0;
    cursor[b1] = 0;
}

// Stage 3: scatter edges (+ synthetic self-loops) into bucket-grouped tmp.
// 16 edges/thread; local rank via LDS returning atomics; one global
// returning atomic per (block, nonempty bucket).
__global__ __launch_bounds__(256) void bucket_scatter_kernel(const int* __restrict__ ei,
                                                             int E, int Etot,
                                                             const int* __restrict__ bucket_base,
                                                             int* __restrict__ cursor,
                                                             int* __restrict__ tmp_dst,
                                                             int* __restrict__ tmp_src) {
    __shared__ int lh[512];
    __shared__ int gb[512];
    for (int i = threadIdx.x; i < 512; i += 256) lh[i] = 0;
    __syncthreads();
    const int base = blockIdx.x * 4096;
    int d[16], s[16], lr[16];
#pragma unroll
    for (int k = 0; k < 16; ++k) {
        const int e = base + k * 256 + threadIdx.x;  // coalesced per k
        if (e < E) { s[k] = ei[e]; d[k] = ei[E + e]; }
        else if (e < Etot) { d[k] = e - E; s[k] = e - E; }  // self-loop
        else { d[k] = -1; s[k] = 0; }
        lr[k] = (d[k] >= 0) ? atomicAdd(&lh[d[k] >> 8], 1) : 0;
    }
    __syncthreads();
    for (int b = threadIdx.x; b < 512; b += 256)
        gb[b] = lh[b] ? atomicAdd(&cursor[b], lh[b]) : 0;
    __syncthreads();
#pragma unroll
    for (int k = 0; k < 16; ++k) {
        if (d[k] >= 0) {
            const int b = d[k] >> 8;
            const int slot = bucket_base[b] + gb[b] + lr[k];
            tmp_dst[slot] = d[k];
            tmp_src[slot] = s[k];
        }
    }
}

// Stage 4: one block per bucket — LDS counting sort by dst&255 producing
// rowstart (direct) and csr_src (LDS-cursor scatter).  Segment order is
// arbitrary (softmax is permutation-invariant).
__global__ __launch_bounds__(256) void bucket_build_kernel(const int* __restrict__ bucket_base,
                                                           const int* __restrict__ tmp_dst,
                                                           const int* __restrict__ tmp_src,
                                                           int* __restrict__ rowstart,
                                                           int* __restrict__ csr_src,
                                                           int N) {
    __shared__ int cnt[256];
    __shared__ int sc[256];
    __shared__ int cur[256];
    const int b = blockIdx.x;
    const int beg = bucket_base[b], end = bucket_base[b + 1];
    const int t = threadIdx.x;
    cnt[t] = 0;
    __syncthreads();
    for (int i = beg + t; i < end; i += 256)
        atomicAdd(&cnt[tmp_dst[i] & 255], 1);
    __syncthreads();
    const int v = cnt[t];
    sc[t] = v;
    __syncthreads();
    for (int off = 1; off < 256; off <<= 1) {
        int tv = (t >= off) ? sc[t - off] : 0;
        __syncthreads();
        sc[t] += tv;
        __syncthreads();
    }
    const int excl = sc[t] - v;
    const int d_out = b * 256 + t;
    if (d_out < N) rowstart[d_out] = beg + excl;
    cur[t] = excl;
    __syncthreads();
    for (int i = beg + t; i < end; i += 256) {
        const int dd = tmp_dst[i];
        const int idx = atomicAdd(&cur[dd & 255], 1);
        csr_src[beg + idx] = tmp_src[i];
    }
}

// ---------------------------------------------------------------------------
// Aggregation layer 1, GROUPED: 4 nodes/wave, 16 lanes/node, lane = 8 ch
// (uint4 gather).  4-edge unroll; invalid slots get p=0 (branch-free).
// ~5.9 TB/s effective gather — near the random-gather floor for bf16 rows.
// ---------------------------------------------------------------------------
__global__ __launch_bounds__(256) void aggregate1_kernel(const unsigned* __restrict__ h1p,
                                                         const float* __restrict__ es,
                                                         const float* __restrict__ ed,
                                                         const int* __restrict__ rowstart,
                                                         const int* __restrict__ csr_src,
                                                         const float* __restrict__ b,
                                                         unsigned* __restrict__ x2p, int N) {
    const int lane = threadIdx.x & 63;
    const int w = (blockIdx.x * 256 + threadIdx.x) >> 6;
    const int l16 = lane & 15;
    const int n = w * 4 + (lane >> 4);
    const int hh = l16 >> 2;  // head 0..3
    const bool valid = n < N;
    const int nc = valid ? n : N - 1;
    const int beg = rowstart[nc];
    const int deg = valid ? rowstart[nc + 1] - beg : 0;
    const float edv = ed[nc * 4 + hh];

    int dmax = deg;
    dmax = max(dmax, __shfl_xor(dmax, 16));
    dmax = max(dmax, __shfl_xor(dmax, 32));

    float acc0 = 0.f, acc1 = 0.f, acc2 = 0.f, acc3 = 0.f;
    float acc4 = 0.f, acc5 = 0.f, acc6 = 0.f, acc7 = 0.f;
    float den = 0.f;
    for (int j = 0; j < dmax; j += 4) {
        const bool va = j < deg, vb = j + 1 < deg, vc = j + 2 < deg, vd = j + 3 < deg;
        const int pa_ = va ? beg + j : 0;
        const int pb_ = vb ? beg + j + 1 : 0;
        const int pc_ = vc ? beg + j + 2 : 0;
        const int pd_ = vd ? beg + j + 3 : 0;
        const int sa = csr_src[pa_];
        const int sb = csr_src[pb_];
        const int sc = csr_src[pc_];
        const int sd = csr_src[pd_];
        const uint4 ua = *(const uint4*)&h1p[(size_t)sa * 64 + l16 * 4];
        const uint4 ub = *(const uint4*)&h1p[(size_t)sb * 64 + l16 * 4];
        const uint4 uc = *(const uint4*)&h1p[(size_t)sc * 64 + l16 * 4];
        const uint4 ud = *(const uint4*)&h1p[(size_t)sd * 64 + l16 * 4];
        const float xa = es[sa * 4 + hh] + edv;
        const float xb = es[sb * 4 + hh] + edv;
        const float xc = es[sc * 4 + hh] + edv;
        const float xd = es[sd * 4 + hh] + edv;
        float qa = __expf(fmaxf(xa, 0.2f * xa));
        float qb = __expf(fmaxf(xb, 0.2f * xb));
        float qc = __expf(fmaxf(xc, 0.2f * xc));
        float qd = __expf(fmaxf(xd, 0.2f * xd));
        qa = va ? qa : 0.f;
        qb = vb ? qb : 0.f;
        qc = vc ? qc : 0.f;
        qd = vd ? qd : 0.f;
        den += (qa + qb) + (qc + qd);
        acc0 = fmaf(qa, bf_lo(ua.x), fmaf(qb, bf_lo(ub.x), fmaf(qc, bf_lo(uc.x), fmaf(qd, bf_lo(ud.x), acc0))));
        acc1 = fmaf(qa, bf_hi(ua.x), fmaf(qb, bf_hi(ub.x), fmaf(qc, bf_hi(uc.x), fmaf(qd, bf_hi(ud.x), acc1))));
        acc2 = fmaf(qa, bf_lo(ua.y), fmaf(qb, bf_lo(ub.y), fmaf(qc, bf_lo(uc.y), fmaf(qd, bf_lo(ud.y), acc2))));
        acc3 = fmaf(qa, bf_hi(ua.y), fmaf(qb, bf_hi(ub.y), fmaf(qc, bf_hi(uc.y), fmaf(qd, bf_hi(ud.y), acc3))));
        acc4 = fmaf(qa, bf_lo(ua.z), fmaf(qb, bf_lo(ub.z), fmaf(qc, bf_lo(uc.z), fmaf(qd, bf_lo(ud.z), acc4))));
        acc5 = fmaf(qa, bf_hi(ua.z), fmaf(qb, bf_hi(ub.z), fmaf(qc, bf_hi(uc.z), fmaf(qd, bf_hi(ud.z), acc5))));
        acc6 = fmaf(qa, bf_lo(ua.w), fmaf(qb, bf_lo(ub.w), fmaf(qc, bf_lo(uc.w), fmaf(qd, bf_lo(ud.w), acc6))));
        acc7 = fmaf(qa, bf_hi(ua.w), fmaf(qb, bf_hi(ub.w), fmaf(qc, bf_hi(uc.w), fmaf(qd, bf_hi(ud.w), acc7))));
    }
    if (valid) {
        const float inv = __builtin_amdgcn_rcpf(den);
        const float4 ba = *(const float4*)&b[l16 * 8];
        const float4 bb = *(const float4*)&b[l16 * 8 + 4];
        float o0 = fmaf(acc0, inv, ba.x); o0 = fmaxf(o0, 0.01f * o0);
        float o1 = fmaf(acc1, inv, ba.y); o1 = fmaxf(o1, 0.01f * o1);
        float o2 = fmaf(acc2, inv, ba.z); o2 = fmaxf(o2, 0.01f * o2);
        float o3 = fmaf(acc3, inv, ba.w); o3 = fmaxf(o3, 0.01f * o3);
        float o4 = fmaf(acc4, inv, bb.x); o4 = fmaxf(o4, 0.01f * o4);
        float o5 = fmaf(acc5, inv, bb.y); o5 = fmaxf(o5, 0.01f * o5);
        float o6 = fmaf(acc6, inv, bb.z); o6 = fmaxf(o6, 0.01f * o6);
        float o7 = fmaf(acc7, inv, bb.w); o7 = fmaxf(o7, 0.01f * o7);
        uint4 o;
        o.x = pack_bf16x2(o0, o1);
        o.y = pack_bf16x2(o2, o3);
        o.z = pack_bf16x2(o4, o5);
        o.w = pack_bf16x2(o6, o7);
        *(uint4*)&x2p[(size_t)n * 64 + l16 * 4] = o;
    }
}

// ---------------------------------------------------------------------------
// Aggregation layer 2, GROUPED: 4 nodes/wave, 16 lanes/node, lane = 4 ch
// (uint2 gather).  Single head.  4-edge unroll.
// ---------------------------------------------------------------------------
__global__ __launch_bounds__(256) void aggregate2_kernel(const unsigned* __restrict__ h2p,
                                                         const float* __restrict__ es,
                                                         const float* __restrict__ ed,
                                                         const int* __restrict__ rowstart,
                                                         const int* __restrict__ csr_src,
                                                         const float* __restrict__ b,
                                                         float* __restrict__ out, int N) {
    const int lane = threadIdx.x & 63;
    const int w = (blockIdx.x * 256 + threadIdx.x) >> 6;
    const int l16 = lane & 15;
    const int n = w * 4 + (lane >> 4);
    const bool valid = n < N;
    const int nc = valid ? n : N - 1;
    const int beg = rowstart[nc];
    const int deg = valid ? rowstart[nc + 1] - beg : 0;
    const float edv = ed[nc];

    int dmax = deg;
    dmax = max(dmax, __shfl_xor(dmax, 16));
    dmax = max(dmax, __shfl_xor(dmax, 32));

    float acc0 = 0.f, acc1 = 0.f, acc2 = 0.f, acc3 = 0.f;
    float den = 0.f;
    for (int j = 0; j < dmax; j += 4) {
        const bool va = j < deg, vb = j + 1 < deg, vc = j + 2 < deg, vd = j + 3 < deg;
        const int pa_ = va ? beg + j : 0;
        const int pb_ = vb ? beg + j + 1 : 0;
        const int pc_ = vc ? beg + j + 2 : 0;
        const int pd_ = vd ? beg + j + 3 : 0;
        const int sa = csr_src[pa_];
        const int sb = csr_src[pb_];
        const int sc = csr_src[pc_];
        const int sd = csr_src[pd_];
        const uint2 ua = *(const uint2*)&h2p[(size_t)sa * 32 + l16 * 2];
        const uint2 ub = *(const uint2*)&h2p[(size_t)sb * 32 + l16 * 2];
        const uint2 uc = *(const uint2*)&h2p[(size_t)sc * 32 + l16 * 2];
        const uint2 ud = *(const uint2*)&h2p[(size_t)sd * 32 + l16 * 2];
        const float xa = es[sa] + edv;
        const float xb = es[sb] + edv;
        const float xc = es[sc] + edv;
        const float xd = es[sd] + edv;
        float qa = __expf(fmaxf(xa, 0.2f * xa));
        float qb = __expf(fmaxf(xb, 0.2f * xb));
        float qc = __expf(fmaxf(xc, 0.2f * xc));
        float qd = __expf(fmaxf(xd, 0.2f * xd));
        qa = va ? qa : 0.f;
        qb = vb ? qb : 0.f;
        qc = vc ? qc : 0.f;
        qd = vd ? qd : 0.f;
        den += (qa + qb) + (qc + qd);
        acc0 = fmaf(qa, bf_lo(ua.x), fmaf(qb, bf_lo(ub.x), fmaf(qc, bf_lo(uc.x), fmaf(qd, bf_lo(ud.x), acc0))));
        acc1 = fmaf(qa, bf_hi(ua.x), fmaf(qb, bf_hi(ub.x), fmaf(qc, bf_hi(uc.x), fmaf(qd, bf_hi(ud.x), acc1))));
        acc2 = fmaf(qa, bf_lo(ua.y), fmaf(qb, bf_lo(ub.y), fmaf(qc, bf_lo(uc.y), fmaf(qd, bf_lo(ud.y), acc2))));
        acc3 = fmaf(qa, bf_hi(ua.y), fmaf(qb, bf_hi(ub.y), fmaf(qc, bf_hi(uc.y), fmaf(qd, bf_hi(ud.y), acc3))));
    }
    if (valid) {
        const float inv = __builtin_amdgcn_rcpf(den);
        const float4 bv = *(const float4*)&b[l16 * 4];
        float4 o;
        o.x = fmaf(acc0, inv, bv.x);
        o.y = fmaf(acc1, inv, bv.y);
        o.z = fmaf(acc2, inv, bv.z);
        o.w = fmaf(acc3, inv, bv.w);
        *(float4*)&out[(size_t)n * 64 + l16 * 4] = o;
    }
}

// ---------------------------------------------------------------------------
extern "C" void kernel_launch(void* const* d_in, const int* in_sizes, int n_in,
                              void* d_out, int out_size, void* d_ws, size_t ws_size,
                              hipStream_t stream) {
    const float* x     = (const float*)d_in[0];
    const int*   ei    = (const int*)d_in[1];
    const float* W1    = (const float*)d_in[2];
    const float* asrc1 = (const float*)d_in[3];
    const float* adst1 = (const float*)d_in[4];
    const float* b1    = (const float*)d_in[5];
    const float* W2    = (const float*)d_in[6];
    const float* asrc2 = (const float*)d_in[7];
    const float* adst2 = (const float*)d_in[8];
    const float* b2    = (const float*)d_in[9];
    float* out = (float*)d_out;

    const int N = in_sizes[0] / 128;
    const int E = in_sizes[1] / 2;
    const int Etot = E + N;
    const int NB = (N + 255) >> 8;  // hi-buckets (<= 512 for N <= 131072)

    // workspace layout (~98 MB)
    char* p = (char*)d_ws;
    auto alloc = [&](size_t bytes) {
        char* q = p;
        p += (bytes + 255) & ~size_t(255);
        return q;
    };
    unsigned short* h1 = (unsigned short*)alloc((size_t)N * 128 * 2);  // bf16 h1
    unsigned* x2p      = (unsigned*)alloc((size_t)N * 64 * 4);         // bf16x2 x2
    unsigned short* h2 = (unsigned short*)alloc((size_t)N * 64 * 2);   // bf16 h2
    float* es1      = (float*)alloc((size_t)N * 4 * 4);
    float* ed1      = (float*)alloc((size_t)N * 4 * 4);
    float* es2      = (float*)alloc((size_t)N * 4);
    float* ed2      = (float*)alloc((size_t)N * 4);
    int*   gcount   = (int*)alloc(512 * 4);
    int*   bucket_base = (int*)alloc(513 * 4);
    int*   cursor   = (int*)alloc(512 * 4);
    int*   rowstart = (int*)alloc((size_t)(N + 1) * 4);
    int*   tmp_dst  = (int*)alloc((size_t)Etot * 4);
    int*   tmp_src  = (int*)alloc((size_t)Etot * 4);
    int*   csr_src  = (int*)alloc((size_t)Etot * 4);
    unsigned* Wb1   = (unsigned*)alloc(2048 * 16);
    unsigned* Wb2   = (unsigned*)alloc(1024 * 16);

    const int nblk16 = (N + 63) / 64;       // MFMA gemms: 4 waves x 16 rows
    const int nwb4 = (N + 15) / 16;         // 4-nodes-per-wave agg kernels
    const int nscat = (Etot + 4095) / 4096; // bucket_scatter blocks

    // weight prep + bucket-counter zero (fused)
    prep_kernel<<<12, 256, 0, stream>>>(W1, W2, Wb1, Wb2, gcount);

    // layer 1 projection (MFMA) + fused scores
    gemm1_kernel<<<nblk16, 256, 0, stream>>>(x, Wb1, asrc1, adst1, h1, es1, ed1, N);

    // CSR by destination via two-level bucket sort
    bucket_hist_kernel<<<512, 256, 0, stream>>>(ei, E, gcount);
    bucket_scan_kernel<<<1, 256, 0, stream>>>(gcount, bucket_base, cursor, rowstart, N, NB, Etot);
    bucket_scatter_kernel<<<nscat, 256, 0, stream>>>(ei, E, Etot, bucket_base, cursor,
                                                     tmp_dst, tmp_src);
    bucket_build_kernel<<<NB, 256, 0, stream>>>(bucket_base, tmp_dst, tmp_src,
                                                rowstart, csr_src, N);

    // layer 1 aggregation (grouped, 4-edge ILP)
    aggregate1_kernel<<<nwb4, 256, 0, stream>>>((const unsigned*)h1, es1, ed1,
                                                rowstart, csr_src, b1, x2p, N);

    // layer 2
    gemm2_kernel<<<nblk16, 256, 0, stream>>>(x2p, Wb2, asrc2, adst2, h2, es2, ed2, N);
    aggregate2_kernel<<<nwb4, 256, 0, stream>>>((const unsigned*)h2, es2, ed2,
                                                rowstart, csr_src, b2, out, N);
}

// Round 16
// 214.227 us; speedup vs baseline: 1.2095x; 1.0645x over previous
//
#include <hip/hip_runtime.h>
#include <hip/hip_bf16.h>

typedef short bf16x8 __attribute__((ext_vector_type(8)));
typedef float f32x4 __attribute__((ext_vector_type(4)));

// --- bf16 pack helpers (RNE) ----------------------------------------------
__device__ __forceinline__ unsigned pack_bf16x2(float lo, float hi) {
    unsigned a = __builtin_bit_cast(unsigned, lo);
    unsigned b = __builtin_bit_cast(unsigned, hi);
    a += 0x7fffu + ((a >> 16) & 1u);
    b += 0x7fffu + ((b >> 16) & 1u);
    return (a >> 16) | (b & 0xffff0000u);
}
__device__ __forceinline__ unsigned short bf16r(float f) {
    unsigned a = __builtin_bit_cast(unsigned, f);
    a += 0x7fffu + ((a >> 16) & 1u);
    return (unsigned short)(a >> 16);
}
__device__ __forceinline__ float bf_lo(unsigned u) {
    return __builtin_bit_cast(float, u << 16);
}
__device__ __forceinline__ float bf_hi(unsigned u) {
    return __builtin_bit_cast(float, u & 0xffff0000u);
}

// ---------------------------------------------------------------------------
// prep + bucket_hist FUSED: blocks 0..11 pack W1/W2 into MFMA-B frag layout
// (block 0 also zeroes gcount first — hist adds from all blocks target
// gcount AFTER a device-memset ordering issue, so gcount is zeroed by
// hipMemsetAsync before this kernel instead); ALL blocks histogram real
// edges per hi-bucket (dst>>8) with LDS aggregation + fire-and-forget adds.
// ---------------------------------------------------------------------------
__global__ __launch_bounds__(256) void prep_hist_kernel(const float* __restrict__ W1,
                                                        const float* __restrict__ W2,
                                                        unsigned* __restrict__ Wb1,
                                                        unsigned* __restrict__ Wb2,
                                                        const int* __restrict__ ei, int E,
                                                        int* __restrict__ gcount) {
    const int t = blockIdx.x * 256 + threadIdx.x;
    if (t < 2048) {
        const int lane = t & 63, kt = (t >> 6) & 3, ct = t >> 8;
        const int col = ct * 16 + (lane & 15);
        const int kb = 8 * (lane >> 4) + 32 * kt;
        uint4 u;
        u.x = pack_bf16x2(W1[(size_t)(kb + 0) * 128 + col], W1[(size_t)(kb + 1) * 128 + col]);
        u.y = pack_bf16x2(W1[(size_t)(kb + 2) * 128 + col], W1[(size_t)(kb + 3) * 128 + col]);
        u.z = pack_bf16x2(W1[(size_t)(kb + 4) * 128 + col], W1[(size_t)(kb + 5) * 128 + col]);
        u.w = pack_bf16x2(W1[(size_t)(kb + 6) * 128 + col], W1[(size_t)(kb + 7) * 128 + col]);
        *(uint4*)&Wb1[t * 4] = u;
    } else if (t < 3072) {
        const int s = t - 2048;
        const int lane = s & 63, kt = (s >> 6) & 3, ct = s >> 8;
        const int col = ct * 16 + (lane & 15);
        const int kb = 8 * (lane >> 4) + 32 * kt;
        uint4 u;
        u.x = pack_bf16x2(W2[(size_t)(kb + 0) * 64 + col], W2[(size_t)(kb + 1) * 64 + col]);
        u.y = pack_bf16x2(W2[(size_t)(kb + 2) * 64 + col], W2[(size_t)(kb + 3) * 64 + col]);
        u.z = pack_bf16x2(W2[(size_t)(kb + 4) * 64 + col], W2[(size_t)(kb + 5) * 64 + col]);
        u.w = pack_bf16x2(W2[(size_t)(kb + 6) * 64 + col], W2[(size_t)(kb + 7) * 64 + col]);
        *(uint4*)&Wb2[s * 4] = u;
    }
    // ---- histogram (all blocks) ----
    __shared__ int h[512];
    for (int i = threadIdx.x; i < 512; i += 256) h[i] = 0;
    __syncthreads();
    for (int e = blockIdx.x * 256 + threadIdx.x; e < E; e += gridDim.x * 256)
        atomicAdd(&h[ei[E + e] >> 8], 1);
    __syncthreads();
    for (int i = threadIdx.x; i < 512; i += 256)
        if (h[i]) atomicAdd(&gcount[i], h[i]);
}

// ---------------------------------------------------------------------------
// GEMM1 + FUSED scores.  h1[N][128] bf16 = bf16(x) @ bf16(W1); es/ed[N][4]
// from fp32 accumulators (head = ct>>1 uniform per ct-tile; 16-lane reduce).
// ---------------------------------------------------------------------------
__global__ __launch_bounds__(256) void gemm1_kernel(const float* __restrict__ x,
                                                    const unsigned* __restrict__ Wb1,
                                                    const float* __restrict__ asrc,
                                                    const float* __restrict__ adst,
                                                    unsigned short* __restrict__ h1,
                                                    float* __restrict__ es,
                                                    float* __restrict__ ed,
                                                    int N) {
    const int wid = threadIdx.x >> 6, lane = threadIdx.x & 63;
    const int row0 = (blockIdx.x * 4 + wid) * 16;
    if (row0 >= N) return;
    const int g = lane >> 4, l16 = lane & 15;
    const int mrow = min(row0 + l16, N - 1);

    bf16x8 afrag[4];
#pragma unroll
    for (int kt = 0; kt < 4; ++kt) {
        const float4 v0 = *(const float4*)&x[(size_t)mrow * 128 + g * 8 + kt * 32];
        const float4 v1 = *(const float4*)&x[(size_t)mrow * 128 + g * 8 + kt * 32 + 4];
        uint4 u;
        u.x = pack_bf16x2(v0.x, v0.y);
        u.y = pack_bf16x2(v0.z, v0.w);
        u.z = pack_bf16x2(v1.x, v1.y);
        u.w = pack_bf16x2(v1.z, v1.w);
        afrag[kt] = __builtin_bit_cast(bf16x8, u);
    }
    float psh[4][4] = {};  // [head][row]
    float pdh[4][4] = {};
#pragma unroll
    for (int ct = 0; ct < 8; ++ct) {
        f32x4 acc = {0.f, 0.f, 0.f, 0.f};
#pragma unroll
        for (int kt = 0; kt < 4; ++kt) {
            const bf16x8 b = __builtin_bit_cast(bf16x8, *(const uint4*)&Wb1[((ct * 4 + kt) * 64 + lane) * 4]);
            acc = __builtin_amdgcn_mfma_f32_16x16x32_bf16(afrag[kt], b, acc, 0, 0, 0);
        }
        const int col = ct * 16 + l16;
        const float as_ = asrc[col], ad_ = adst[col];
        const int hh = ct >> 1;
#pragma unroll
        for (int r = 0; r < 4; ++r) {
            psh[hh][r] = fmaf(acc[r], as_, psh[hh][r]);
            pdh[hh][r] = fmaf(acc[r], ad_, pdh[hh][r]);
        }
#pragma unroll
        for (int r = 0; r < 4; ++r) {
            const int row = row0 + g * 4 + r;
            if (row < N) h1[(size_t)row * 128 + col] = bf16r(acc[r]);
        }
    }
#pragma unroll
    for (int hh = 0; hh < 4; ++hh)
#pragma unroll
        for (int r = 0; r < 4; ++r) {
#pragma unroll
            for (int off = 1; off <= 8; off <<= 1) {
                psh[hh][r] += __shfl_xor(psh[hh][r], off);
                pdh[hh][r] += __shfl_xor(pdh[hh][r], off);
            }
        }
    if (l16 == 0) {
#pragma unroll
        for (int r = 0; r < 4; ++r) {
            const int row = row0 + g * 4 + r;
            if (row < N) {
#pragma unroll
                for (int hh = 0; hh < 4; ++hh) {
                    es[row * 4 + hh] = psh[hh][r];
                    ed[row * 4 + hh] = pdh[hh][r];
                }
            }
        }
    }
}

// ---------------------------------------------------------------------------
// GEMM2 + FUSED scores (single head): h2[N][64] bf16 = x2(bf16) @ bf16(W2).
// ---------------------------------------------------------------------------
__global__ __launch_bounds__(256) void gemm2_kernel(const unsigned* __restrict__ x2p,
                                                    const unsigned* __restrict__ Wb2,
                                                    const float* __restrict__ asrc,
                                                    const float* __restrict__ adst,
                                                    unsigned short* __restrict__ h2,
                                                    float* __restrict__ es,
                                                    float* __restrict__ ed,
                                                    int N) {
    const int wid = threadIdx.x >> 6, lane = threadIdx.x & 63;
    const int row0 = (blockIdx.x * 4 + wid) * 16;
    if (row0 >= N) return;
    const int g = lane >> 4, l16 = lane & 15;
    const int mrow = min(row0 + l16, N - 1);

    bf16x8 afrag[4];
#pragma unroll
    for (int kt = 0; kt < 4; ++kt)
        afrag[kt] = __builtin_bit_cast(bf16x8, *(const uint4*)&x2p[(size_t)mrow * 64 + g * 4 + kt * 16]);
    float ps[4] = {}, pd[4] = {};
#pragma unroll
    for (int ct = 0; ct < 4; ++ct) {
        f32x4 acc = {0.f, 0.f, 0.f, 0.f};
#pragma unroll
        for (int kt = 0; kt < 4; ++kt) {
            const bf16x8 b = __builtin_bit_cast(bf16x8, *(const uint4*)&Wb2[((ct * 4 + kt) * 64 + lane) * 4]);
            acc = __builtin_amdgcn_mfma_f32_16x16x32_bf16(afrag[kt], b, acc, 0, 0, 0);
        }
        const int col = ct * 16 + l16;
        const float as_ = asrc[col], ad_ = adst[col];
#pragma unroll
        for (int r = 0; r < 4; ++r) {
            ps[r] = fmaf(acc[r], as_, ps[r]);
            pd[r] = fmaf(acc[r], ad_, pd[r]);
        }
#pragma unroll
        for (int r = 0; r < 4; ++r) {
            const int row = row0 + g * 4 + r;
            if (row < N) h2[(size_t)row * 64 + col] = bf16r(acc[r]);
        }
    }
#pragma unroll
    for (int r = 0; r < 4; ++r) {
#pragma unroll
        for (int off = 1; off <= 8; off <<= 1) {
            ps[r] += __shfl_xor(ps[r], off);
            pd[r] += __shfl_xor(pd[r], off);
        }
    }
    if (l16 == 0) {
#pragma unroll
        for (int r = 0; r < 4; ++r) {
            const int row = row0 + g * 4 + r;
            if (row < N) { es[row] = ps[r]; ed[row] = pd[r]; }
        }
    }
}

// ---------------------------------------------------------------------------
// Stage 2 (1 block): counts += per-bucket self-loop count, exclusive scan ->
// bucket_base[0..NB] (slot space), zero cursors, rowstart[N] = Etot.
// ---------------------------------------------------------------------------
__global__ __launch_bounds__(256) void bucket_scan_kernel(const int* __restrict__ gcount,
                                                          int* __restrict__ bucket_base,
                                                          int* __restrict__ cursor,
                                                          int* __restrict__ rowstart,
                                                          int N, int NB, int Etot) {
    __shared__ int pairs[256];
    const int t = threadIdx.x;
    const int b0 = 2 * t, b1 = 2 * t + 1;
    int v0 = 0, v1 = 0;
    if (b0 < NB) v0 = gcount[b0] + min(256, N - b0 * 256);  // + self-loops
    if (b1 < NB) v1 = gcount[b1] + min(256, N - b1 * 256);
    const int s = v0 + v1;
    pairs[t] = s;
    __syncthreads();
    for (int off = 1; off < 256; off <<= 1) {
        int tv = (t >= off) ? pairs[t - off] : 0;
        __syncthreads();
        pairs[t] += tv;
        __syncthreads();
    }
    const int base = pairs[t] - s;  // exclusive over pairs
    if (b0 < NB) bucket_base[b0] = base;
    if (b1 < NB) bucket_base[b1] = base + v0;
    if (t == 255) {
        bucket_base[NB] = pairs[255];  // == Etot
        rowstart[N] = Etot;
    }
    cursor[b0] = 0;
    cursor[b1] = 0;
}

// ---------------------------------------------------------------------------
// Stage 3: scatter edges (+ synthetic self-loops) into bucket-grouped tmp,
// PACKED as uint2 (dst,src) — one 8B store per edge (half the write-allocate
// lines vs two parallel 4B arrays).  Local rank via LDS returning atomics;
// one global returning atomic per (block, nonempty bucket).
// ---------------------------------------------------------------------------
__global__ __launch_bounds__(256) void bucket_scatter_kernel(const int* __restrict__ ei,
                                                             int E, int Etot,
                                                             const int* __restrict__ bucket_base,
                                                             int* __restrict__ cursor,
                                                             uint2* __restrict__ tmp) {
    __shared__ int lh[512];
    __shared__ int gb[512];
    for (int i = threadIdx.x; i < 512; i += 256) lh[i] = 0;
    __syncthreads();
    const int base = blockIdx.x * 4096;
    int d[16], s[16], lr[16];
#pragma unroll
    for (int k = 0; k < 16; ++k) {
        const int e = base + k * 256 + threadIdx.x;  // coalesced per k
        if (e < E) { s[k] = ei[e]; d[k] = ei[E + e]; }
        else if (e < Etot) { d[k] = e - E; s[k] = e - E; }  // self-loop
        else { d[k] = -1; s[k] = 0; }
        lr[k] = (d[k] >= 0) ? atomicAdd(&lh[d[k] >> 8], 1) : 0;
    }
    __syncthreads();
    for (int b = threadIdx.x; b < 512; b += 256)
        gb[b] = lh[b] ? atomicAdd(&cursor[b], lh[b]) : 0;
    __syncthreads();
#pragma unroll
    for (int k = 0; k < 16; ++k) {
        if (d[k] >= 0) {
            const int b = d[k] >> 8;
            tmp[bucket_base[b] + gb[b] + lr[k]] = make_uint2((unsigned)d[k], (unsigned)s[k]);
        }
    }
}

// ---------------------------------------------------------------------------
// Stage 4: one block per bucket — LDS counting sort by dst&255 producing
// rowstart (direct) and csr_src (LDS-cursor scatter).  Segment order is
// arbitrary (softmax is permutation-invariant).
// ---------------------------------------------------------------------------
__global__ __launch_bounds__(256) void bucket_build_kernel(const int* __restrict__ bucket_base,
                                                           const uint2* __restrict__ tmp,
                                                           int* __restrict__ rowstart,
                                                           int* __restrict__ csr_src,
                                                           int N) {
    __shared__ int cnt[256];
    __shared__ int sc[256];
    __shared__ int cur[256];
    const int b = blockIdx.x;
    const int beg = bucket_base[b], end = bucket_base[b + 1];
    const int t = threadIdx.x;
    cnt[t] = 0;
    __syncthreads();
    for (int i = beg + t; i < end; i += 256)
        atomicAdd(&cnt[tmp[i].x & 255u], 1);
    __syncthreads();
    const int v = cnt[t];
    sc[t] = v;
    __syncthreads();
    for (int off = 1; off < 256; off <<= 1) {
        int tv = (t >= off) ? sc[t - off] : 0;
        __syncthreads();
        sc[t] += tv;
        __syncthreads();
    }
    const int excl = sc[t] - v;
    const int d_out = b * 256 + t;
    if (d_out < N) rowstart[d_out] = beg + excl;
    cur[t] = excl;
    __syncthreads();
    for (int i = beg + t; i < end; i += 256) {
        const uint2 e = tmp[i];
        const int idx = atomicAdd(&cur[e.x & 255u], 1);
        csr_src[beg + idx] = (int)e.y;
    }
}

// ---------------------------------------------------------------------------
// Aggregation layer 1, GROUPED: 4 nodes/wave, 16 lanes/node, lane = 8 ch
// (uint4 gather).  4-edge unroll; invalid slots get p=0 (branch-free).
// ---------------------------------------------------------------------------
__global__ __launch_bounds__(256) void aggregate1_kernel(const unsigned* __restrict__ h1p,
                                                         const float* __restrict__ es,
                                                         const float* __restrict__ ed,
                                                         const int* __restrict__ rowstart,
                                                         const int* __restrict__ csr_src,
                                                         const float* __restrict__ b,
                                                         unsigned* __restrict__ x2p, int N) {
    const int lane = threadIdx.x & 63;
    const int w = (blockIdx.x * 256 + threadIdx.x) >> 6;
    const int l16 = lane & 15;
    const int n = w * 4 + (lane >> 4);
    const int hh = l16 >> 2;  // head 0..3
    const bool valid = n < N;
    const int nc = valid ? n : N - 1;
    const int beg = rowstart[nc];
    const int deg = valid ? rowstart[nc + 1] - beg : 0;
    const float edv = ed[nc * 4 + hh];

    int dmax = deg;
    dmax = max(dmax, __shfl_xor(dmax, 16));
    dmax = max(dmax, __shfl_xor(dmax, 32));

    float acc0 = 0.f, acc1 = 0.f, acc2 = 0.f, acc3 = 0.f;
    float acc4 = 0.f, acc5 = 0.f, acc6 = 0.f, acc7 = 0.f;
    float den = 0.f;
    for (int j = 0; j < dmax; j += 4) {
        const bool va = j < deg, vb = j + 1 < deg, vc = j + 2 < deg, vd = j + 3 < deg;
        const int pa_ = va ? beg + j : 0;
        const int pb_ = vb ? beg + j + 1 : 0;
        const int pc_ = vc ? beg + j + 2 : 0;
        const int pd_ = vd ? beg + j + 3 : 0;
        const int sa = csr_src[pa_];
        const int sb = csr_src[pb_];
        const int sc = csr_src[pc_];
        const int sd = csr_src[pd_];
        const uint4 ua = *(const uint4*)&h1p[(size_t)sa * 64 + l16 * 4];
        const uint4 ub = *(const uint4*)&h1p[(size_t)sb * 64 + l16 * 4];
        const uint4 uc = *(const uint4*)&h1p[(size_t)sc * 64 + l16 * 4];
        const uint4 ud = *(const uint4*)&h1p[(size_t)sd * 64 + l16 * 4];
        const float xa = es[sa * 4 + hh] + edv;
        const float xb = es[sb * 4 + hh] + edv;
        const float xc = es[sc * 4 + hh] + edv;
        const float xd = es[sd * 4 + hh] + edv;
        float qa = __expf(fmaxf(xa, 0.2f * xa));
        float qb = __expf(fmaxf(xb, 0.2f * xb));
        float qc = __expf(fmaxf(xc, 0.2f * xc));
        float qd = __expf(fmaxf(xd, 0.2f * xd));
        qa = va ? qa : 0.f;
        qb = vb ? qb : 0.f;
        qc = vc ? qc : 0.f;
        qd = vd ? qd : 0.f;
        den += (qa + qb) + (qc + qd);
        acc0 = fmaf(qa, bf_lo(ua.x), fmaf(qb, bf_lo(ub.x), fmaf(qc, bf_lo(uc.x), fmaf(qd, bf_lo(ud.x), acc0))));
        acc1 = fmaf(qa, bf_hi(ua.x), fmaf(qb, bf_hi(ub.x), fmaf(qc, bf_hi(uc.x), fmaf(qd, bf_hi(ud.x), acc1))));
        acc2 = fmaf(qa, bf_lo(ua.y), fmaf(qb, bf_lo(ub.y), fmaf(qc, bf_lo(uc.y), fmaf(qd, bf_lo(ud.y), acc2))));
        acc3 = fmaf(qa, bf_hi(ua.y), fmaf(qb, bf_hi(ub.y), fmaf(qc, bf_hi(uc.y), fmaf(qd, bf_hi(ud.y), acc3))));
        acc4 = fmaf(qa, bf_lo(ua.z), fmaf(qb, bf_lo(ub.z), fmaf(qc, bf_lo(uc.z), fmaf(qd, bf_lo(ud.z), acc4))));
        acc5 = fmaf(qa, bf_hi(ua.z), fmaf(qb, bf_hi(ub.z), fmaf(qc, bf_hi(uc.z), fmaf(qd, bf_hi(ud.z), acc5))));
        acc6 = fmaf(qa, bf_lo(ua.w), fmaf(qb, bf_lo(ub.w), fmaf(qc, bf_lo(uc.w), fmaf(qd, bf_lo(ud.w), acc6))));
        acc7 = fmaf(qa, bf_hi(ua.w), fmaf(qb, bf_hi(ub.w), fmaf(qc, bf_hi(uc.w), fmaf(qd, bf_hi(ud.w), acc7))));
    }
    if (valid) {
        const float inv = __builtin_amdgcn_rcpf(den);
        const float4 ba = *(const float4*)&b[l16 * 8];
        const float4 bb = *(const float4*)&b[l16 * 8 + 4];
        float o0 = fmaf(acc0, inv, ba.x); o0 = fmaxf(o0, 0.01f * o0);
        float o1 = fmaf(acc1, inv, ba.y); o1 = fmaxf(o1, 0.01f * o1);
        float o2 = fmaf(acc2, inv, ba.z); o2 = fmaxf(o2, 0.01f * o2);
        float o3 = fmaf(acc3, inv, ba.w); o3 = fmaxf(o3, 0.01f * o3);
        float o4 = fmaf(acc4, inv, bb.x); o4 = fmaxf(o4, 0.01f * o4);
        float o5 = fmaf(acc5, inv, bb.y); o5 = fmaxf(o5, 0.01f * o5);
        float o6 = fmaf(acc6, inv, bb.z); o6 = fmaxf(o6, 0.01f * o6);
        float o7 = fmaf(acc7, inv, bb.w); o7 = fmaxf(o7, 0.01f * o7);
        uint4 o;
        o.x = pack_bf16x2(o0, o1);
        o.y = pack_bf16x2(o2, o3);
        o.z = pack_bf16x2(o4, o5);
        o.w = pack_bf16x2(o6, o7);
        *(uint4*)&x2p[(size_t)n * 64 + l16 * 4] = o;
    }
}

// ---------------------------------------------------------------------------
// Aggregation layer 2, GROUPED: 4 nodes/wave, 16 lanes/node, lane = 4 ch
// (uint2 gather).  Single head.  4-edge unroll.
// ---------------------------------------------------------------------------
__global__ __launch_bounds__(256) void aggregate2_kernel(const unsigned* __restrict__ h2p,
                                                         const float* __restrict__ es,
                                                         const float* __restrict__ ed,
                                                         const int* __restrict__ rowstart,
                                                         const int* __restrict__ csr_src,
                                                         const float* __restrict__ b,
                                                         float* __restrict__ out, int N) {
    const int lane = threadIdx.x & 63;
    const int w = (blockIdx.x * 256 + threadIdx.x) >> 6;
    const int l16 = lane & 15;
    const int n = w * 4 + (lane >> 4);
    const bool valid = n < N;
    const int nc = valid ? n : N - 1;
    const int beg = rowstart[nc];
    const int deg = valid ? rowstart[nc + 1] - beg : 0;
    const float edv = ed[nc];

    int dmax = deg;
    dmax = max(dmax, __shfl_xor(dmax, 16));
    dmax = max(dmax, __shfl_xor(dmax, 32));

    float acc0 = 0.f, acc1 = 0.f, acc2 = 0.f, acc3 = 0.f;
    float den = 0.f;
    for (int j = 0; j < dmax; j += 4) {
        const bool va = j < deg, vb = j + 1 < deg, vc = j + 2 < deg, vd = j + 3 < deg;
        const int pa_ = va ? beg + j : 0;
        const int pb_ = vb ? beg + j + 1 : 0;
        const int pc_ = vc ? beg + j + 2 : 0;
        const int pd_ = vd ? beg + j + 3 : 0;
        const int sa = csr_src[pa_];
        const int sb = csr_src[pb_];
        const int sc = csr_src[pc_];
        const int sd = csr_src[pd_];
        const uint2 ua = *(const uint2*)&h2p[(size_t)sa * 32 + l16 * 2];
        const uint2 ub = *(const uint2*)&h2p[(size_t)sb * 32 + l16 * 2];
        const uint2 uc = *(const uint2*)&h2p[(size_t)sc * 32 + l16 * 2];
        const uint2 ud = *(const uint2*)&h2p[(size_t)sd * 32 + l16 * 2];
        const float xa = es[sa] + edv;
        const float xb = es[sb] + edv;
        const float xc = es[sc] + edv;
        const float xd = es[sd] + edv;
        float qa = __expf(fmaxf(xa, 0.2f * xa));
        float qb = __expf(fmaxf(xb, 0.2f * xb));
        float qc = __expf(fmaxf(xc, 0.2f * xc));
        float qd = __expf(fmaxf(xd, 0.2f * xd));
        qa = va ? qa : 0.f;
        qb = vb ? qb : 0.f;
        qc = vc ? qc : 0.f;
        qd = vd ? qd : 0.f;
        den += (qa + qb) + (qc + qd);
        acc0 = fmaf(qa, bf_lo(ua.x), fmaf(qb, bf_lo(ub.x), fmaf(qc, bf_lo(uc.x), fmaf(qd, bf_lo(ud.x), acc0))));
        acc1 = fmaf(qa, bf_hi(ua.x), fmaf(qb, bf_hi(ub.x), fmaf(qc, bf_hi(uc.x), fmaf(qd, bf_hi(ud.x), acc1))));
        acc2 = fmaf(qa, bf_lo(ua.y), fmaf(qb, bf_lo(ub.y), fmaf(qc, bf_lo(uc.y), fmaf(qd, bf_lo(ud.y), acc2))));
        acc3 = fmaf(qa, bf_hi(ua.y), fmaf(qb, bf_hi(ub.y), fmaf(qc, bf_hi(uc.y), fmaf(qd, bf_hi(ud.y), acc3))));
    }
    if (valid) {
        const float inv = __builtin_amdgcn_rcpf(den);
        const float4 bv = *(const float4*)&b[l16 * 4];
        float4 o;
        o.x = fmaf(acc0, inv, bv.x);
        o.y = fmaf(acc1, inv, bv.y);
        o.z = fmaf(acc2, inv, bv.z);
        o.w = fmaf(acc3, inv, bv.w);
        *(float4*)&out[(size_t)n * 64 + l16 * 4] = o;
    }
}

// ---------------------------------------------------------------------------
extern "C" void kernel_launch(void* const* d_in, const int* in_sizes, int n_in,
                              void* d_out, int out_size, void* d_ws, size_t ws_size,
                              hipStream_t stream) {
    const float* x     = (const float*)d_in[0];
    const int*   ei    = (const int*)d_in[1];
    const float* W1    = (const float*)d_in[2];
    const float* asrc1 = (const float*)d_in[3];
    const float* adst1 = (const float*)d_in[4];
    const float* b1    = (const float*)d_in[5];
    const float* W2    = (const float*)d_in[6];
    const float* asrc2 = (const float*)d_in[7];
    const float* adst2 = (const float*)d_in[8];
    const float* b2    = (const float*)d_in[9];
    float* out = (float*)d_out;

    const int N = in_sizes[0] / 128;
    const int E = in_sizes[1] / 2;
    const int Etot = E + N;
    const int NB = (N + 255) >> 8;  // hi-buckets (<= 512 for N <= 131072)

    // workspace layout (~92 MB)
    char* p = (char*)d_ws;
    auto alloc = [&](size_t bytes) {
        char* q = p;
        p += (bytes + 255) & ~size_t(255);
        return q;
    };
    unsigned short* h1 = (unsigned short*)alloc((size_t)N * 128 * 2);  // bf16 h1
    unsigned* x2p      = (unsigned*)alloc((size_t)N * 64 * 4);         // bf16x2 x2
    unsigned short* h2 = (unsigned short*)alloc((size_t)N * 64 * 2);   // bf16 h2
    float* es1      = (float*)alloc((size_t)N * 4 * 4);
    float* ed1      = (float*)alloc((size_t)N * 4 * 4);
    float* es2      = (float*)alloc((size_t)N * 4);
    float* ed2      = (float*)alloc((size_t)N * 4);
    int*   gcount   = (int*)alloc(512 * 4);
    int*   bucket_base = (int*)alloc(513 * 4);
    int*   cursor   = (int*)alloc(512 * 4);
    int*   rowstart = (int*)alloc((size_t)(N + 1) * 4);
    uint2* tmp      = (uint2*)alloc((size_t)Etot * 8);
    int*   csr_src  = (int*)alloc((size_t)Etot * 4);
    unsigned* Wb1   = (unsigned*)alloc(2048 * 16);
    unsigned* Wb2   = (unsigned*)alloc(1024 * 16);

    const int nblk16 = (N + 63) / 64;       // MFMA gemms: 4 waves x 16 rows
    const int nwb4 = (N + 15) / 16;         // 4-nodes-per-wave agg kernels
    const int nscat = (Etot + 4095) / 4096; // bucket_scatter blocks

    // zero bucket counters, then fused prep + histogram
    hipMemsetAsync(gcount, 0, 512 * 4, stream);
    prep_hist_kernel<<<512, 256, 0, stream>>>(W1, W2, Wb1, Wb2, ei, E, gcount);

    // layer 1 projection (MFMA) + fused scores
    gemm1_kernel<<<nblk16, 256, 0, stream>>>(x, Wb1, asrc1, adst1, h1, es1, ed1, N);

    // CSR by destination via two-level bucket sort (uint2-packed tmp)
    bucket_scan_kernel<<<1, 256, 0, stream>>>(gcount, bucket_base, cursor, rowstart, N, NB, Etot);
    bucket_scatter_kernel<<<nscat, 256, 0, stream>>>(ei, E, Etot, bucket_base, cursor, tmp);
    bucket_build_kernel<<<NB, 256, 0, stream>>>(bucket_base, tmp, rowstart, csr_src, N);

    // layer 1 aggregation (grouped, 4-edge ILP)
    aggregate1_kernel<<<nwb4, 256, 0, stream>>>((const unsigned*)h1, es1, ed1,
                                                rowstart, csr_src, b1, x2p, N);

    // layer 2
    gemm2_kernel<<<nblk16, 256, 0, stream>>>(x2p, Wb2, asrc2, adst2, h2, es2, ed2, N);
    aggregate2_kernel<<<nwb4, 256, 0, stream>>>((const unsigned*)h2, es2, ed2,
                                                rowstart, csr_src, b2, out, N);
}